// Round 14
// baseline (574.068 us; speedup 1.0000x reference)
//
#include <hip/hip_runtime.h>
#include <hip/hip_fp16.h>
#include <math.h>

#define N_ENT 100000
#define N_EDGE 500000
#define N_REL 200
// DIM=64, HEADS=4, HD=256

typedef short bf16x8 __attribute__((ext_vector_type(8)));
typedef _Float16 f16x8 __attribute__((ext_vector_type(8)));
typedef float f32x4 __attribute__((ext_vector_type(4)));

__device__ __forceinline__ float fast_tanh(float x) {
    float xc = fminf(x, 15.f);
    float e = __expf(2.f * xc);
    return 1.f - 2.f * __builtin_amdgcn_rcpf(e + 1.f);
}

__device__ __forceinline__ unsigned short f2bf(float f) {
    unsigned u = __float_as_uint(f);
    unsigned r = u + 0x7FFF + ((u >> 16) & 1);   // RNE
    return (unsigned short)(r >> 16);
}

__device__ __forceinline__ unsigned pack_half2(float a, float b) {
    __half2 h = __floats2half2_rn(a, b);
    return *reinterpret_cast<unsigned*>(&h);
}

// ---------------------------------------------------------------------------
// Merged prep: hist (records per-edge row slot), cvt_emb (bf16 + fp16),
// cvt_wT, cvt_woT.
#define HIST_B 1954
#define EMB_B  2048
#define WT_B   128
#define WOT_B  64
__global__ __launch_bounds__(256) void prep_kernel(
    const float* __restrict__ entity, unsigned short* __restrict__ emb_bf,
    __half* __restrict__ emb_h,
    const float* __restrict__ W0, const float* __restrict__ W1,
    unsigned short* __restrict__ wT,
    const float* __restrict__ Wo, __half* __restrict__ woT,
    const int* __restrict__ eidx, int* __restrict__ counts,
    int* __restrict__ eoff)
{
    int bid = blockIdx.x;
    if (bid < HIST_B) {
        int e = bid * 256 + threadIdx.x;
        if (e < N_EDGE) eoff[e] = atomicAdd(&counts[eidx[e]], 1);
    } else if (bid < HIST_B + EMB_B) {
        int b = bid - HIST_B;
        const int nquads = N_ENT * 64 / 4;
        for (int i = b * 256 + threadIdx.x; i < nquads; i += EMB_B * 256) {
            float4 v = ((const float4*)entity)[i];
            ushort4 o;
            o.x = f2bf(v.x); o.y = f2bf(v.y); o.z = f2bf(v.z); o.w = f2bf(v.w);
            ((ushort4*)emb_bf)[i] = o;
            uint2 oh;
            oh.x = pack_half2(v.x, v.y);
            oh.y = pack_half2(v.z, v.w);
            ((uint2*)emb_h)[i] = oh;
        }
    } else if (bid < HIST_B + EMB_B + WT_B) {
        int idx = (bid - HIST_B - EMB_B) * 256 + threadIdx.x;   // 0..32767
        int mat = idx >> 14;
        int rem = idx & 16383;
        int col = rem >> 6;
        int k   = rem & 63;
        const float* W = (mat == 0) ? W0 : W1;
        wT[idx] = f2bf(W[k * 256 + col]);
    } else {
        int idx = (bid - HIST_B - EMB_B - WT_B) * 256 + threadIdx.x;  // 0..16383
        int d = idx >> 8;
        int k = idx & 255;
        woT[idx] = __float2half(Wo[k * 64 + d]);
    }
}

// ---------------------------------------------------------------------------
// MFMA attention projection, ONE mat per block. C layout (HW-verified):
// col=lane&15, row=(lane>>4)*4+reg.
__global__ __launch_bounds__(256) void proj_mfma_kernel(
    const unsigned short* __restrict__ emb_bf,   // [N][64] bf16
    const unsigned short* __restrict__ wT,       // [2*256][64] bf16
    const float* __restrict__ att0, const float* __restrict__ att1,
    float* __restrict__ p0, float* __restrict__ p1, int nrows, int nb)
{
    const int mat = (blockIdx.x >= nb) ? 1 : 0;
    const int rb  = blockIdx.x - mat * nb;
    const float* att = (mat == 0) ? att0 : att1;
    float* p         = (mat == 0) ? p0 : p1;
    const unsigned short* wbase = wT + (size_t)mat * 256 * 64;

    const int wv   = threadIdx.x >> 6;
    const int lane = threadIdx.x & 63;
    const int r4   = lane >> 4;
    const int cl   = lane & 15;
    const int rowbase = rb * 64 + wv * 16;

    int ra = min(rowbase + cl, nrows - 1);
    bf16x8 a0 = *(const bf16x8*)(emb_bf + (size_t)ra * 64 + 8 * r4);
    bf16x8 a1 = *(const bf16x8*)(emb_bf + (size_t)ra * 64 + 8 * r4 + 32);

    float pacc[4][4];   // [head][j]
#pragma unroll
    for (int head = 0; head < 4; ++head) {
        float vsum[4] = {0.f, 0.f, 0.f, 0.f};
#pragma unroll
        for (int sub = 0; sub < 4; ++sub) {
            int col = head * 64 + sub * 16 + cl;
            const unsigned short* wp = wbase + (size_t)col * 64 + 8 * r4;
            bf16x8 b0 = *(const bf16x8*)(wp);
            bf16x8 b1 = *(const bf16x8*)(wp + 32);
            f32x4 c = {0.f, 0.f, 0.f, 0.f};
            c = __builtin_amdgcn_mfma_f32_16x16x32_bf16(a0, b0, c, 0, 0, 0);
            c = __builtin_amdgcn_mfma_f32_16x16x32_bf16(a1, b1, c, 0, 0, 0);
            float av = att[head * 64 + sub * 16 + cl];
#pragma unroll
            for (int j = 0; j < 4; ++j)
                vsum[j] = fmaf(fast_tanh(c[j]), av, vsum[j]);
        }
#pragma unroll
        for (int j = 0; j < 4; ++j) {
            float v = vsum[j];
            v += __shfl_xor(v, 1, 64);
            v += __shfl_xor(v, 2, 64);
            v += __shfl_xor(v, 4, 64);
            v += __shfl_xor(v, 8, 64);
            pacc[head][j] = v;
        }
    }
    if (cl == 0) {
#pragma unroll
        for (int j = 0; j < 4; ++j) {
            int row = rowbase + r4 * 4 + j;
            if (row < nrows) {
                *(float4*)(p + (size_t)row * 4) = make_float4(
                    pacc[0][j], pacc[1][j], pacc[2][j], pacc[3][j]);
            }
        }
    }
}

// ---------------------------------------------------------------------------
// VALU projection for relations (only 200 rows).
__global__ __launch_bounds__(256) void proj_gemm_kernel(
    const float* __restrict__ emb,
    const float* __restrict__ W0,
    const float* __restrict__ att0,
    float* __restrict__ p0,
    int nrows)
{
    __shared__ float e_lds[64][68];
    __shared__ float w0_lds[64][64];
    __shared__ float red[4][4][64];

    const int t    = threadIdx.x;
    const int wv   = t >> 6;
    const int lane = t & 63;
    const int er   = t & 15;
    const int d0   = (t >> 4) * 4;
    const int base = blockIdx.x * 64;

#pragma unroll
    for (int i = 0; i < 4; ++i) {
        int f = t + 256 * i;
        int row = f >> 4, c4 = f & 15;
        int gr = min(base + row, nrows - 1);
        float4 v = *(const float4*)(emb + (size_t)gr * 64 + 4 * c4);
        *(float4*)&e_lds[row][4 * c4] = v;
    }

    float p0s[4][4];

    for (int head = 0; head < 4; ++head) {
        {
            int k0 = t >> 4, c4 = t & 15;
#pragma unroll
            for (int kk = 0; kk < 4; ++kk) {
                int k = k0 + 16 * kk;
                *(float4*)&w0_lds[k][4 * c4] =
                    *(const float4*)(W0 + (size_t)k * 256 + head * 64 + 4 * c4);
            }
        }
        __syncthreads();

        float acc0[4][4] = {};
        for (int k4 = 0; k4 < 16; ++k4) {
            float4 z0 = *(const float4*)&e_lds[er +  0][4 * k4];
            float4 z1 = *(const float4*)&e_lds[er + 16][4 * k4];
            float4 z2 = *(const float4*)&e_lds[er + 32][4 * k4];
            float4 z3 = *(const float4*)&e_lds[er + 48][4 * k4];
            const float zr[4][4] = {
                {z0.x, z0.y, z0.z, z0.w},
                {z1.x, z1.y, z1.z, z1.w},
                {z2.x, z2.y, z2.z, z2.w},
                {z3.x, z3.y, z3.z, z3.w}};
#pragma unroll
            for (int jj = 0; jj < 4; ++jj) {
                float4 w0v = *(const float4*)&w0_lds[4 * k4 + jj][d0];
#pragma unroll
                for (int i = 0; i < 4; ++i) {
                    float zj = zr[i][jj];
                    acc0[i][0] = fmaf(zj, w0v.x, acc0[i][0]);
                    acc0[i][1] = fmaf(zj, w0v.y, acc0[i][1]);
                    acc0[i][2] = fmaf(zj, w0v.z, acc0[i][2]);
                    acc0[i][3] = fmaf(zj, w0v.w, acc0[i][3]);
                }
            }
        }

        float4 av0 = *(const float4*)(att0 + head * 64 + d0);
#pragma unroll
        for (int i = 0; i < 4; ++i) {
            float v = fast_tanh(acc0[i][0]) * av0.x
                    + fast_tanh(acc0[i][1]) * av0.y
                    + fast_tanh(acc0[i][2]) * av0.z
                    + fast_tanh(acc0[i][3]) * av0.w;
            v += __shfl_xor(v, 16, 64);
            v += __shfl_xor(v, 32, 64);
            p0s[head][i] = v;
        }
        __syncthreads();
    }

    if (lane < 16) {
#pragma unroll
        for (int h = 0; h < 4; ++h)
#pragma unroll
            for (int i = 0; i < 4; ++i)
                red[wv][h][lane + 16 * i] = p0s[h][i];
    }
    __syncthreads();
    if (t < 64) {
        int row = base + t;
        if (row < nrows) {
            float4 pv;
            pv.x = red[0][0][t] + red[1][0][t] + red[2][0][t] + red[3][0][t];
            pv.y = red[0][1][t] + red[1][1][t] + red[2][1][t] + red[3][1][t];
            pv.z = red[0][2][t] + red[1][2][t] + red[2][2][t] + red[3][2][t];
            pv.w = red[0][3][t] + red[1][3][t] + red[2][3][t] + red[3][3][t];
            *(float4*)(p0 + (size_t)row * 4) = pv;
        }
    }
}

// ---------------------------------------------------------------------------
__global__ __launch_bounds__(1024) void scan_kernel(
    const int* __restrict__ counts, int* __restrict__ row_start)
{
    __shared__ int wsum[16];
    __shared__ int carry_s;
    const int lane = threadIdx.x & 63;
    const int wid  = threadIdx.x >> 6;
    if (threadIdx.x == 0) carry_s = 0;
    __syncthreads();
    for (int base = 0; base < N_ENT; base += 4096) {
        int i0 = base + (int)threadIdx.x * 4;
        int4 v = make_int4(0, 0, 0, 0);
        if (i0 + 3 < N_ENT) v = *(const int4*)(counts + i0);
        else {
            if (i0 + 0 < N_ENT) v.x = counts[i0 + 0];
            if (i0 + 1 < N_ENT) v.y = counts[i0 + 1];
            if (i0 + 2 < N_ENT) v.z = counts[i0 + 2];
            if (i0 + 3 < N_ENT) v.w = counts[i0 + 3];
        }
        int s1 = v.x + v.y, s2 = s1 + v.z, tsum = s2 + v.w;
        int incl = tsum;
#pragma unroll
        for (int off = 1; off < 64; off <<= 1) {
            int t = __shfl_up(incl, off, 64);
            if (lane >= off) incl += t;
        }
        if (lane == 63) wsum[wid] = incl;
        __syncthreads();                              // A
        int wave_off = 0;
#pragma unroll
        for (int w = 0; w < 16; ++w)
            wave_off += (w < wid) ? wsum[w] : 0;
        int carry = carry_s;
        int excl = carry + wave_off + (incl - tsum);
        if (i0 + 3 < N_ENT) {
            *(int4*)(row_start + i0) = make_int4(excl, excl + v.x, excl + s1, excl + s2);
        } else {
            if (i0 + 0 < N_ENT) row_start[i0 + 0] = excl;
            if (i0 + 1 < N_ENT) row_start[i0 + 1] = excl + v.x;
            if (i0 + 2 < N_ENT) row_start[i0 + 2] = excl + s1;
            if (i0 + 3 < N_ENT) row_start[i0 + 3] = excl + s2;
        }
        __syncthreads();                              // B
        if (threadIdx.x == 1023) carry_s = carry + wave_off + incl;
    }
    __syncthreads();
    if (threadIdx.x == 0) row_start[N_ENT] = carry_s;
}

// ---------------------------------------------------------------------------
// Per-edge scatter, NO atomics: slot precomputed in prep (eoff).
__global__ __launch_bounds__(256) void scatter_score_kernel(
    const int* __restrict__ eidx, const int* __restrict__ etype,
    const float* __restrict__ ph, const float* __restrict__ pt,
    const float* __restrict__ pr,
    const int* __restrict__ row_start, const int* __restrict__ eoff,
    int* __restrict__ csr_col, float* __restrict__ csr_a)
{
    int e = blockIdx.x * 256 + threadIdx.x;
    if (e >= N_EDGE) return;
    int hn = eidx[e];
    int tn = eidx[N_EDGE + e];
    int r  = etype[e];
    float4 a = *(const float4*)(ph + (size_t)hn * 4);
    float4 b = *(const float4*)(pt + (size_t)tn * 4);
    float4 c = *(const float4*)(pr + (size_t)r * 4);
    float s0 = a.x + b.x + c.x;
    float s1 = a.y + b.y + c.y;
    float s2 = a.z + b.z + c.z;
    float s3 = a.w + b.w + c.w;
    s0 = s0 >= 0.f ? s0 : 0.01f * s0;
    s1 = s1 >= 0.f ? s1 : 0.01f * s1;
    s2 = s2 >= 0.f ? s2 : 0.01f * s2;
    s3 = s3 >= 0.f ? s3 : 0.01f * s3;
    float4 ev = make_float4(__expf(s0), __expf(s1), __expf(s2), __expf(s3));
    int pos = row_start[hn] + eoff[e];
    csr_col[pos] = tn;
    *(float4*)(csr_a + (size_t)pos * 4) = ev;
}

// ---------------------------------------------------------------------------
// Row-wise softmax normalize (standalone): csr_a[p][h] *= 0.9/(sum+eps).
__global__ __launch_bounds__(256) void normalize_kernel(
    const int* __restrict__ row_start, float* __restrict__ csr_a)
{
    const int wid  = threadIdx.x >> 6;
    const int lane = threadIdx.x & 63;
    const int n = blockIdx.x * 4 + wid;
    if (n >= N_ENT) return;
    const int s   = row_start[n];
    const int end = row_start[n + 1];
    const int nf  = (end - s) * 4;

    float sum = 0.f;
    for (int f = lane; f < nf; f += 64)
        sum += csr_a[(size_t)s * 4 + f];
#pragma unroll
    for (int off = 4; off < 64; off <<= 1)
        sum += __shfl_xor(sum, off, 64);
    float scale = 0.9f * __builtin_amdgcn_rcpf(sum + 1e-16f);
    for (int f = lane; f < nf; f += 64)
        csr_a[(size_t)s * 4 + f] *= scale;
}

// ---------------------------------------------------------------------------
// Head-phased SpMM: one dispatch per (iteration, head-phase). Lane =
// (row-group r = lane>>3, col-octet c = lane&7): 8 rows/wave, each 8-lane
// group walks its row's edges gathering ONE 128B line per edge (cols
// phase*64..+63 of the tail's row). No shuffles, no cross-lane reduce.
// Working set per dispatch = 12.8 MB of distinct lines (vs 51 MB full-row).
template <bool FIRST>
__global__ __launch_bounds__(256) void spmm_head_kernel(
    const __half* __restrict__ Zin,      // FIRST: emb_h [N][64]; else [N][256]
    const __half* __restrict__ emb_h,    // [N][64] fp16 (alpha*Z0 term)
    const int* __restrict__ row_start, const int* __restrict__ csr_col,
    const float* __restrict__ csr_a, __half* __restrict__ Zout, int phase)
{
    const int wave = threadIdx.x >> 6;
    const int lane = threadIdx.x & 63;
    const int r = lane >> 3;
    const int c = lane & 7;
    const int n = (blockIdx.x * 4 + wave) * 8 + r;
    if (n >= N_ENT) return;

    const _Float16* zin = (const _Float16*)Zin;
    float acc[8];
    {
        f16x8 z0 = *(const f16x8*)((const _Float16*)emb_h + (size_t)n * 64 + 8 * c);
#pragma unroll
        for (int k = 0; k < 8; ++k) acc[k] = 0.1f * (float)z0[k];
    }
    const int s = row_start[n], end = row_start[n + 1];
    for (int e = s; e < end; ++e) {
        float a  = csr_a[(size_t)e * 4 + phase];
        int col  = csr_col[e];
        const _Float16* zp = FIRST
            ? zin + (size_t)col * 64 + 8 * c
            : zin + (size_t)col * 256 + phase * 64 + 8 * c;
        f16x8 z = *(const f16x8*)zp;
#pragma unroll
        for (int k = 0; k < 8; ++k) acc[k] = fmaf(a, (float)z[k], acc[k]);
    }
    uint4 o;
    o.x = pack_half2(acc[0], acc[1]);
    o.y = pack_half2(acc[2], acc[3]);
    o.z = pack_half2(acc[4], acc[5]);
    o.w = pack_half2(acc[6], acc[7]);
    *(uint4*)((_Float16*)Zout + (size_t)n * 256 + phase * 64 + 8 * c) = o;
}

// ---------------------------------------------------------------------------
// Fused: 5th SpMM (head-phased: wave = phase) + MFMA output projection.
// Block = 16 rows; wave wv gathers cols wv*64..+63 for all 16 rows (2
// groups-of-8 passes), fills its LDS col-slice; barrier; MFMA epilogue.
__global__ __launch_bounds__(256) void spmm_out_fused_kernel(
    const __half* __restrict__ Zin, const __half* __restrict__ emb_h,
    const int* __restrict__ row_start, const int* __restrict__ csr_col,
    const float* __restrict__ csr_a,
    const __half* __restrict__ woT,    // [64][256] fp16 (d-major)
    float* __restrict__ out)           // [N][64]
{
    __shared__ _Float16 zl[16][264];
    const int wv   = threadIdx.x >> 6;   // = phase
    const int lane = threadIdx.x & 63;
    const int r = lane >> 3;
    const int c = lane & 7;
    const int base = blockIdx.x * 16;
    const _Float16* zin = (const _Float16*)Zin;

#pragma unroll
    for (int half16 = 0; half16 < 2; ++half16) {
        const int n = base + half16 * 8 + r;
        float acc[8];
        {
            f16x8 z0 = *(const f16x8*)((const _Float16*)emb_h + (size_t)n * 64 + 8 * c);
#pragma unroll
            for (int k = 0; k < 8; ++k) acc[k] = 0.1f * (float)z0[k];
        }
        const int s = row_start[n], end = row_start[n + 1];
        for (int e = s; e < end; ++e) {
            float a = csr_a[(size_t)e * 4 + wv];
            int col = csr_col[e];
            f16x8 z = *(const f16x8*)(zin + (size_t)col * 256 + wv * 64 + 8 * c);
#pragma unroll
            for (int k = 0; k < 8; ++k) acc[k] = fmaf(a, (float)z[k], acc[k]);
        }
        uint4 o;
        o.x = pack_half2(acc[0], acc[1]);
        o.y = pack_half2(acc[2], acc[3]);
        o.z = pack_half2(acc[4], acc[5]);
        o.w = pack_half2(acc[6], acc[7]);
        *(uint4*)&zl[half16 * 8 + r][wv * 64 + 8 * c] = o;
    }
    __syncthreads();

    const int cl = lane & 15;
    const int r4 = lane >> 4;
    f16x8 a[8];
#pragma unroll
    for (int ks = 0; ks < 8; ++ks)
        a[ks] = *(const f16x8*)&zl[cl][ks * 32 + 8 * r4];

    const _Float16* wcol = (const _Float16*)woT + (size_t)(wv * 16 + cl) * 256 + 8 * r4;
    f32x4 cc = {0.f, 0.f, 0.f, 0.f};
#pragma unroll
    for (int ks = 0; ks < 8; ++ks) {
        f16x8 b = *(const f16x8*)(wcol + ks * 32);
        cc = __builtin_amdgcn_mfma_f32_16x16x32_f16(a[ks], b, cc, 0, 0, 0);
    }
#pragma unroll
    for (int j = 0; j < 4; ++j) {
        int row = base + r4 * 4 + j;
        out[(size_t)row * 64 + wv * 16 + cl] = cc[j];
    }
}

// ---------------------------------------------------------------------------
extern "C" void kernel_launch(void* const* d_in, const int* in_sizes, int n_in,
                              void* d_out, int out_size, void* d_ws, size_t ws_size,
                              hipStream_t stream)
{
    const float* entity = (const float*)d_in[0];
    const float* rel    = (const float*)d_in[1];
    const float* W_h    = (const float*)d_in[2];
    const float* W_t    = (const float*)d_in[3];
    const float* W_r    = (const float*)d_in[4];
    const float* att_h  = (const float*)d_in[5];
    const float* att_t  = (const float*)d_in[6];
    const float* att_r  = (const float*)d_in[7];
    const float* W_o    = (const float*)d_in[8];
    const int*   eidx   = (const int*)d_in[9];   // [2,E]
    const int*   etype  = (const int*)d_in[10];  // [E]
    float* out = (float*)d_out;

    char* ws = (char*)d_ws;
    size_t off = 0;
    auto alloc = [&](size_t bytes) -> void* {
        void* p = ws + off;
        off += (bytes + 255) & ~(size_t)255;
        return p;
    };
    float* p_h      = (float*)alloc((size_t)N_ENT * 4 * 4);
    float* p_t      = (float*)alloc((size_t)N_ENT * 4 * 4);
    float* p_r      = (float*)alloc((size_t)N_REL * 4 * 4);
    int*   counts   = (int*)alloc((size_t)N_ENT * 4);
    int*   row_start= (int*)alloc(((size_t)N_ENT + 1) * 4);
    int*   eoff     = (int*)alloc((size_t)N_EDGE * 4);
    int*   csr_col  = (int*)alloc((size_t)N_EDGE * 4);
    float* csr_a    = (float*)alloc((size_t)N_EDGE * 4 * 4);
    __half* Zh_a    = (__half*)alloc((size_t)N_ENT * 256 * 2);
    __half* Zh_b    = (__half*)alloc((size_t)N_ENT * 256 * 2);
    unsigned short* emb_bf = (unsigned short*)alloc((size_t)N_ENT * 64 * 2);
    __half* emb_h   = (__half*)alloc((size_t)N_ENT * 64 * 2);
    unsigned short* wT     = (unsigned short*)alloc((size_t)2 * 256 * 64 * 2);
    __half* woT     = (__half*)alloc((size_t)64 * 256 * 2);

    hipMemsetAsync(counts, 0, (size_t)N_ENT * 4, stream);

    // merged prep: hist (+slot record) + bf16/fp16 conversions
    prep_kernel<<<HIST_B + EMB_B + WT_B + WOT_B, 256, 0, stream>>>(
        entity, emb_bf, emb_h, W_h, W_t, wT, W_o, woT, eidx, counts, eoff);

    // projections: h/t via MFMA (mat-split grid), relations via VALU
    const int nb = (N_ENT + 63) / 64;
    proj_mfma_kernel<<<2 * nb, 256, 0, stream>>>(
        emb_bf, wT, att_h, att_t, p_h, p_t, N_ENT, nb);
    proj_gemm_kernel<<<(N_REL + 63) / 64, 256, 0, stream>>>(
        rel, W_r, att_r, p_r, N_REL);

    scan_kernel<<<1, 1024, 0, stream>>>(counts, row_start);
    scatter_score_kernel<<<(N_EDGE + 255) / 256, 256, 0, stream>>>(
        eidx, etype, p_h, p_t, p_r, row_start, eoff, csr_col, csr_a);
    normalize_kernel<<<(N_ENT + 3) / 4, 256, 0, stream>>>(row_start, csr_a);

    // power iteration, head-phased: each iteration = 4 phase dispatches
    // (phase working set = 12.8 MB of cache lines). Iter 5 fused with outproj.
    const int sg = (N_ENT + 31) / 32;   // blocks: 4 waves x 8 rows
    for (int ph = 0; ph < 4; ++ph)
        spmm_head_kernel<true><<<sg, 256, 0, stream>>>(
            emb_h, emb_h, row_start, csr_col, csr_a, Zh_b, ph);
    for (int ph = 0; ph < 4; ++ph)
        spmm_head_kernel<false><<<sg, 256, 0, stream>>>(
            Zh_b, emb_h, row_start, csr_col, csr_a, Zh_a, ph);
    for (int ph = 0; ph < 4; ++ph)
        spmm_head_kernel<false><<<sg, 256, 0, stream>>>(
            Zh_a, emb_h, row_start, csr_col, csr_a, Zh_b, ph);
    for (int ph = 0; ph < 4; ++ph)
        spmm_head_kernel<false><<<sg, 256, 0, stream>>>(
            Zh_b, emb_h, row_start, csr_col, csr_a, Zh_a, ph);
    spmm_out_fused_kernel<<<N_ENT / 16, 256, 0, stream>>>(
        Zh_a, emb_h, row_start, csr_col, csr_a, woT, out);
}

// Round 15
// 403.386 us; speedup vs baseline: 1.4231x; 1.4231x over previous
//
#include <hip/hip_runtime.h>
#include <hip/hip_fp16.h>
#include <math.h>

#define N_ENT 100000
#define N_EDGE 500000
#define N_REL 200
// DIM=64, HEADS=4, HD=256

typedef short bf16x8 __attribute__((ext_vector_type(8)));
typedef _Float16 f16x8 __attribute__((ext_vector_type(8)));
typedef float f32x4 __attribute__((ext_vector_type(4)));

__device__ __forceinline__ float fast_tanh(float x) {
    float xc = fminf(x, 15.f);
    float e = __expf(2.f * xc);
    return 1.f - 2.f * __builtin_amdgcn_rcpf(e + 1.f);
}

__device__ __forceinline__ unsigned short f2bf(float f) {
    unsigned u = __float_as_uint(f);
    unsigned r = u + 0x7FFF + ((u >> 16) & 1);   // RNE
    return (unsigned short)(r >> 16);
}

__device__ __forceinline__ unsigned pack_half2(float a, float b) {
    __half2 h = __floats2half2_rn(a, b);
    return *reinterpret_cast<unsigned*>(&h);
}

// ---------------------------------------------------------------------------
// Merged prep: hist (records per-edge row slot), cvt_emb (bf16 + fp16),
// cvt_wT, cvt_woT. All independent jobs, one dispatch.
#define HIST_B 1954
#define EMB_B  2048
#define WT_B   128
#define WOT_B  64
__global__ __launch_bounds__(256) void prep_kernel(
    const float* __restrict__ entity, unsigned short* __restrict__ emb_bf,
    __half* __restrict__ emb_h,
    const float* __restrict__ W0, const float* __restrict__ W1,
    unsigned short* __restrict__ wT,
    const float* __restrict__ Wo, __half* __restrict__ woT,
    const int* __restrict__ eidx, int* __restrict__ counts,
    int* __restrict__ eoff)
{
    int bid = blockIdx.x;
    if (bid < HIST_B) {
        int e = bid * 256 + threadIdx.x;
        if (e < N_EDGE) eoff[e] = atomicAdd(&counts[eidx[e]], 1);
    } else if (bid < HIST_B + EMB_B) {
        int b = bid - HIST_B;
        const int nquads = N_ENT * 64 / 4;
        for (int i = b * 256 + threadIdx.x; i < nquads; i += EMB_B * 256) {
            float4 v = ((const float4*)entity)[i];
            ushort4 o;
            o.x = f2bf(v.x); o.y = f2bf(v.y); o.z = f2bf(v.z); o.w = f2bf(v.w);
            ((ushort4*)emb_bf)[i] = o;
            uint2 oh;
            oh.x = pack_half2(v.x, v.y);
            oh.y = pack_half2(v.z, v.w);
            ((uint2*)emb_h)[i] = oh;
        }
    } else if (bid < HIST_B + EMB_B + WT_B) {
        int idx = (bid - HIST_B - EMB_B) * 256 + threadIdx.x;   // 0..32767
        int mat = idx >> 14;
        int rem = idx & 16383;
        int col = rem >> 6;
        int k   = rem & 63;
        const float* W = (mat == 0) ? W0 : W1;
        wT[idx] = f2bf(W[k * 256 + col]);
    } else {
        int idx = (bid - HIST_B - EMB_B - WT_B) * 256 + threadIdx.x;  // 0..16383
        int d = idx >> 8;
        int k = idx & 255;
        woT[idx] = __float2half(Wo[k * 64 + d]);
    }
}

// ---------------------------------------------------------------------------
// MFMA attention projection, ONE mat per block. C layout (HW-verified):
// col=lane&15, row=(lane>>4)*4+reg.
__global__ __launch_bounds__(256) void proj_mfma_kernel(
    const unsigned short* __restrict__ emb_bf,   // [N][64] bf16
    const unsigned short* __restrict__ wT,       // [2*256][64] bf16
    const float* __restrict__ att0, const float* __restrict__ att1,
    float* __restrict__ p0, float* __restrict__ p1, int nrows, int nb)
{
    const int mat = (blockIdx.x >= nb) ? 1 : 0;
    const int rb  = blockIdx.x - mat * nb;
    const float* att = (mat == 0) ? att0 : att1;
    float* p         = (mat == 0) ? p0 : p1;
    const unsigned short* wbase = wT + (size_t)mat * 256 * 64;

    const int wv   = threadIdx.x >> 6;
    const int lane = threadIdx.x & 63;
    const int r4   = lane >> 4;
    const int cl   = lane & 15;
    const int rowbase = rb * 64 + wv * 16;

    int ra = min(rowbase + cl, nrows - 1);
    bf16x8 a0 = *(const bf16x8*)(emb_bf + (size_t)ra * 64 + 8 * r4);
    bf16x8 a1 = *(const bf16x8*)(emb_bf + (size_t)ra * 64 + 8 * r4 + 32);

    float pacc[4][4];   // [head][j]
#pragma unroll
    for (int head = 0; head < 4; ++head) {
        float vsum[4] = {0.f, 0.f, 0.f, 0.f};
#pragma unroll
        for (int sub = 0; sub < 4; ++sub) {
            int col = head * 64 + sub * 16 + cl;
            const unsigned short* wp = wbase + (size_t)col * 64 + 8 * r4;
            bf16x8 b0 = *(const bf16x8*)(wp);
            bf16x8 b1 = *(const bf16x8*)(wp + 32);
            f32x4 c = {0.f, 0.f, 0.f, 0.f};
            c = __builtin_amdgcn_mfma_f32_16x16x32_bf16(a0, b0, c, 0, 0, 0);
            c = __builtin_amdgcn_mfma_f32_16x16x32_bf16(a1, b1, c, 0, 0, 0);
            float av = att[head * 64 + sub * 16 + cl];
#pragma unroll
            for (int j = 0; j < 4; ++j)
                vsum[j] = fmaf(fast_tanh(c[j]), av, vsum[j]);
        }
#pragma unroll
        for (int j = 0; j < 4; ++j) {
            float v = vsum[j];
            v += __shfl_xor(v, 1, 64);
            v += __shfl_xor(v, 2, 64);
            v += __shfl_xor(v, 4, 64);
            v += __shfl_xor(v, 8, 64);
            pacc[head][j] = v;
        }
    }
    if (cl == 0) {
#pragma unroll
        for (int j = 0; j < 4; ++j) {
            int row = rowbase + r4 * 4 + j;
            if (row < nrows) {
                *(float4*)(p + (size_t)row * 4) = make_float4(
                    pacc[0][j], pacc[1][j], pacc[2][j], pacc[3][j]);
            }
        }
    }
}

// ---------------------------------------------------------------------------
// VALU projection for relations (only 200 rows).
__global__ __launch_bounds__(256) void proj_gemm_kernel(
    const float* __restrict__ emb,
    const float* __restrict__ W0,
    const float* __restrict__ att0,
    float* __restrict__ p0,
    int nrows)
{
    __shared__ float e_lds[64][68];
    __shared__ float w0_lds[64][64];
    __shared__ float red[4][4][64];

    const int t    = threadIdx.x;
    const int wv   = t >> 6;
    const int lane = t & 63;
    const int er   = t & 15;
    const int d0   = (t >> 4) * 4;
    const int base = blockIdx.x * 64;

#pragma unroll
    for (int i = 0; i < 4; ++i) {
        int f = t + 256 * i;
        int row = f >> 4, c4 = f & 15;
        int gr = min(base + row, nrows - 1);
        float4 v = *(const float4*)(emb + (size_t)gr * 64 + 4 * c4);
        *(float4*)&e_lds[row][4 * c4] = v;
    }

    float p0s[4][4];

    for (int head = 0; head < 4; ++head) {
        {
            int k0 = t >> 4, c4 = t & 15;
#pragma unroll
            for (int kk = 0; kk < 4; ++kk) {
                int k = k0 + 16 * kk;
                *(float4*)&w0_lds[k][4 * c4] =
                    *(const float4*)(W0 + (size_t)k * 256 + head * 64 + 4 * c4);
            }
        }
        __syncthreads();

        float acc0[4][4] = {};
        for (int k4 = 0; k4 < 16; ++k4) {
            float4 z0 = *(const float4*)&e_lds[er +  0][4 * k4];
            float4 z1 = *(const float4*)&e_lds[er + 16][4 * k4];
            float4 z2 = *(const float4*)&e_lds[er + 32][4 * k4];
            float4 z3 = *(const float4*)&e_lds[er + 48][4 * k4];
            const float zr[4][4] = {
                {z0.x, z0.y, z0.z, z0.w},
                {z1.x, z1.y, z1.z, z1.w},
                {z2.x, z2.y, z2.z, z2.w},
                {z3.x, z3.y, z3.z, z3.w}};
#pragma unroll
            for (int jj = 0; jj < 4; ++jj) {
                float4 w0v = *(const float4*)&w0_lds[4 * k4 + jj][d0];
#pragma unroll
                for (int i = 0; i < 4; ++i) {
                    float zj = zr[i][jj];
                    acc0[i][0] = fmaf(zj, w0v.x, acc0[i][0]);
                    acc0[i][1] = fmaf(zj, w0v.y, acc0[i][1]);
                    acc0[i][2] = fmaf(zj, w0v.z, acc0[i][2]);
                    acc0[i][3] = fmaf(zj, w0v.w, acc0[i][3]);
                }
            }
        }

        float4 av0 = *(const float4*)(att0 + head * 64 + d0);
#pragma unroll
        for (int i = 0; i < 4; ++i) {
            float v = fast_tanh(acc0[i][0]) * av0.x
                    + fast_tanh(acc0[i][1]) * av0.y
                    + fast_tanh(acc0[i][2]) * av0.z
                    + fast_tanh(acc0[i][3]) * av0.w;
            v += __shfl_xor(v, 16, 64);
            v += __shfl_xor(v, 32, 64);
            p0s[head][i] = v;
        }
        __syncthreads();
    }

    if (lane < 16) {
#pragma unroll
        for (int h = 0; h < 4; ++h)
#pragma unroll
            for (int i = 0; i < 4; ++i)
                red[wv][h][lane + 16 * i] = p0s[h][i];
    }
    __syncthreads();
    if (t < 64) {
        int row = base + t;
        if (row < nrows) {
            float4 pv;
            pv.x = red[0][0][t] + red[1][0][t] + red[2][0][t] + red[3][0][t];
            pv.y = red[0][1][t] + red[1][1][t] + red[2][1][t] + red[3][1][t];
            pv.z = red[0][2][t] + red[1][2][t] + red[2][2][t] + red[3][2][t];
            pv.w = red[0][3][t] + red[1][3][t] + red[2][3][t] + red[3][3][t];
            *(float4*)(p0 + (size_t)row * 4) = pv;
        }
    }
}

// ---------------------------------------------------------------------------
__global__ __launch_bounds__(1024) void scan_kernel(
    const int* __restrict__ counts, int* __restrict__ row_start)
{
    __shared__ int wsum[16];
    __shared__ int carry_s;
    const int lane = threadIdx.x & 63;
    const int wid  = threadIdx.x >> 6;
    if (threadIdx.x == 0) carry_s = 0;
    __syncthreads();
    for (int base = 0; base < N_ENT; base += 4096) {
        int i0 = base + (int)threadIdx.x * 4;
        int4 v = make_int4(0, 0, 0, 0);
        if (i0 + 3 < N_ENT) v = *(const int4*)(counts + i0);
        else {
            if (i0 + 0 < N_ENT) v.x = counts[i0 + 0];
            if (i0 + 1 < N_ENT) v.y = counts[i0 + 1];
            if (i0 + 2 < N_ENT) v.z = counts[i0 + 2];
            if (i0 + 3 < N_ENT) v.w = counts[i0 + 3];
        }
        int s1 = v.x + v.y, s2 = s1 + v.z, tsum = s2 + v.w;
        int incl = tsum;
#pragma unroll
        for (int off = 1; off < 64; off <<= 1) {
            int t = __shfl_up(incl, off, 64);
            if (lane >= off) incl += t;
        }
        if (lane == 63) wsum[wid] = incl;
        __syncthreads();                              // A
        int wave_off = 0;
#pragma unroll
        for (int w = 0; w < 16; ++w)
            wave_off += (w < wid) ? wsum[w] : 0;
        int carry = carry_s;
        int excl = carry + wave_off + (incl - tsum);
        if (i0 + 3 < N_ENT) {
            *(int4*)(row_start + i0) = make_int4(excl, excl + v.x, excl + s1, excl + s2);
        } else {
            if (i0 + 0 < N_ENT) row_start[i0 + 0] = excl;
            if (i0 + 1 < N_ENT) row_start[i0 + 1] = excl + v.x;
            if (i0 + 2 < N_ENT) row_start[i0 + 2] = excl + s1;
            if (i0 + 3 < N_ENT) row_start[i0 + 3] = excl + s2;
        }
        __syncthreads();                              // B
        if (threadIdx.x == 1023) carry_s = carry + wave_off + incl;
    }
    __syncthreads();
    if (threadIdx.x == 0) row_start[N_ENT] = carry_s;
}

// ---------------------------------------------------------------------------
// Per-edge scatter, NO atomics: slot precomputed in prep (eoff).
__global__ __launch_bounds__(256) void scatter_score_kernel(
    const int* __restrict__ eidx, const int* __restrict__ etype,
    const float* __restrict__ ph, const float* __restrict__ pt,
    const float* __restrict__ pr,
    const int* __restrict__ row_start, const int* __restrict__ eoff,
    int* __restrict__ csr_col, float* __restrict__ csr_a)
{
    int e = blockIdx.x * 256 + threadIdx.x;
    if (e >= N_EDGE) return;
    int hn = eidx[e];
    int tn = eidx[N_EDGE + e];
    int r  = etype[e];
    float4 a = *(const float4*)(ph + (size_t)hn * 4);
    float4 b = *(const float4*)(pt + (size_t)tn * 4);
    float4 c = *(const float4*)(pr + (size_t)r * 4);
    float s0 = a.x + b.x + c.x;
    float s1 = a.y + b.y + c.y;
    float s2 = a.z + b.z + c.z;
    float s3 = a.w + b.w + c.w;
    s0 = s0 >= 0.f ? s0 : 0.01f * s0;
    s1 = s1 >= 0.f ? s1 : 0.01f * s1;
    s2 = s2 >= 0.f ? s2 : 0.01f * s2;
    s3 = s3 >= 0.f ? s3 : 0.01f * s3;
    float4 ev = make_float4(__expf(s0), __expf(s1), __expf(s2), __expf(s3));
    int pos = row_start[hn] + eoff[e];
    csr_col[pos] = tn;
    *(float4*)(csr_a + (size_t)pos * 4) = ev;
}

// ---------------------------------------------------------------------------
// Pair-gather SpMM row body (round-12 proven). lane = (half=lane>>5, j=lane&31);
// one 16B gather covers cols 8j..8j+7 of edge (e+half) -> 2 edges/instr.
// FIRST: source is emb_h [N][64] head-broadcast (col 8*(j&7)); else [N][256].
// NORM: scale csr_a in-register and persist normalized values.
template <bool FIRST, bool NORM>
__device__ __forceinline__ void spmm_row_pair(
    int n, int lane, float scale,
    const __half* __restrict__ Zin_h, const float* __restrict__ emb,
    const int* __restrict__ row_start, const int* __restrict__ csr_col,
    float* __restrict__ csr_a, float acc[8])
{
    const int half = lane >> 5;
    const int j    = lane & 31;
    const int hd   = j >> 3;          // head of cols 8j..8j+7
    const int s    = row_start[n];
    const int end  = row_start[n + 1];
    const _Float16* zin = (const _Float16*)Zin_h;

    {   // init: half 0 carries 0.1*z0 (emb fp32 cols 8*(j&7)..+7, exact)
        const float* z0p = emb + (size_t)n * 64 + 8 * (j & 7);
        float4 z0a = *(const float4*)(z0p);
        float4 z0b = *(const float4*)(z0p + 4);
        float m = (half == 0) ? 0.1f : 0.f;
        acc[0] = m * z0a.x; acc[1] = m * z0a.y; acc[2] = m * z0a.z; acc[3] = m * z0a.w;
        acc[4] = m * z0b.x; acc[5] = m * z0b.y; acc[6] = m * z0b.z; acc[7] = m * z0b.w;
    }
    float accB[8] = {0.f, 0.f, 0.f, 0.f, 0.f, 0.f, 0.f, 0.f};

    for (int b = s; b < end; b += 16) {
        const int nb = min(16, end - b);
        int   cl = (lane < nb) ? csr_col[b + lane] : 0;
        float al = (lane < nb * 4) ? csr_a[(size_t)b * 4 + lane] : 0.f;
        if (NORM) {
            al *= scale;                               // head lane&3
            if (lane < nb * 4) csr_a[(size_t)b * 4 + lane] = al;
        }
        for (int e = 0; e < nb; e += 4) {
            int iA = half ? min(e + 1, nb - 1) : e;
            int iB = half ? min(e + 3, nb - 1) : min(e + 2, nb - 1);
            int cA = __shfl(cl, iA, 64);
            int cB = __shfl(cl, iB, 64);
            float aA = __shfl(al, iA * 4 + hd, 64);
            float aB = __shfl(al, iB * 4 + hd, 64);
            aA = (e + half < nb) ? aA : 0.f;
            aB = (e + 2 + half < nb) ? aB : 0.f;
            f16x8 zA, zB;
            if (FIRST) {
                zA = *(const f16x8*)(zin + (size_t)cA * 64 + 8 * (j & 7));
                zB = *(const f16x8*)(zin + (size_t)cB * 64 + 8 * (j & 7));
            } else {
                zA = *(const f16x8*)(zin + (size_t)cA * 256 + 8 * j);
                zB = *(const f16x8*)(zin + (size_t)cB * 256 + 8 * j);
            }
#pragma unroll
            for (int k = 0; k < 8; ++k) {
                acc[k]  = fmaf(aA, (float)zA[k], acc[k]);
                accB[k] = fmaf(aB, (float)zB[k], accB[k]);
            }
        }
    }
#pragma unroll
    for (int k = 0; k < 8; ++k) {
        float v = acc[k] + accB[k];
        v += __shfl_xor(v, 32, 64);
        acc[k] = v;
    }
}

__device__ __forceinline__ void store_row_h(
    __half* __restrict__ dst256, int lane, const float acc[8])
{
    if (lane < 32) {
        uint4 o;
        o.x = pack_half2(acc[0], acc[1]);
        o.y = pack_half2(acc[2], acc[3]);
        o.z = pack_half2(acc[4], acc[5]);
        o.w = pack_half2(acc[6], acc[7]);
        *(uint4*)(dst256 + 8 * lane) = o;
    }
}

// ---------------------------------------------------------------------------
// Fused softmax-normalize + first SpMM. Wave per row.
__global__ __launch_bounds__(256) void norm_spmm1_kernel(
    const float* __restrict__ emb, const __half* __restrict__ emb_h,
    const int* __restrict__ row_start, const int* __restrict__ csr_col,
    float* __restrict__ csr_a, __half* __restrict__ Zout)
{
    const int wave = threadIdx.x >> 6;
    const int lane = threadIdx.x & 63;
    const int n = blockIdx.x * 4 + wave;
    const int s   = row_start[n];
    const int end = row_start[n + 1];
    const int nf  = (end - s) * 4;

    float sum = 0.f;
    for (int f = lane; f < nf; f += 64)
        sum += csr_a[(size_t)s * 4 + f];
#pragma unroll
    for (int off = 4; off < 64; off <<= 1)
        sum += __shfl_xor(sum, off, 64);
    float scale = 0.9f * __builtin_amdgcn_rcpf(sum + 1e-16f);  // head lane&3

    float acc[8];
    spmm_row_pair<true, true>(n, lane, scale, emb_h, emb,
                              row_start, csr_col, csr_a, acc);
    store_row_h(Zout + (size_t)n * 256, lane, acc);
}

// ---------------------------------------------------------------------------
// Standalone SpMM step (iterations 2..4).
__global__ __launch_bounds__(256) void spmm_kernel(
    const __half* __restrict__ Zin, const float* __restrict__ emb,
    const int* __restrict__ row_start, const int* __restrict__ csr_col,
    float* __restrict__ csr_a, __half* __restrict__ Zout)
{
    const int wave = threadIdx.x >> 6;
    const int lane = threadIdx.x & 63;
    const int n = blockIdx.x * 4 + wave;
    float acc[8];
    spmm_row_pair<false, false>(n, lane, 1.f, Zin, emb,
                                row_start, csr_col, csr_a, acc);
    store_row_h(Zout + (size_t)n * 256, lane, acc);
}

// ---------------------------------------------------------------------------
// Fused: 5th SpMM + output projection. Block = 16 rows.
__global__ __launch_bounds__(256) void spmm_out_fused_kernel(
    const __half* __restrict__ Zin, const float* __restrict__ emb,
    const int* __restrict__ row_start, const int* __restrict__ csr_col,
    float* __restrict__ csr_a,
    const __half* __restrict__ woT,    // [64][256] fp16 (d-major)
    float* __restrict__ out)           // [N][64]
{
    __shared__ _Float16 zl[16][264];
    const int wv   = threadIdx.x >> 6;
    const int lane = threadIdx.x & 63;
    const int base = blockIdx.x * 16;

#pragma unroll
    for (int rr = 0; rr < 4; ++rr) {
        int n = base + wv * 4 + rr;
        float acc[8];
        spmm_row_pair<false, false>(n, lane, 1.f, Zin, emb,
                                    row_start, csr_col, csr_a, acc);
        if (lane < 32) {
            uint4 o;
            o.x = pack_half2(acc[0], acc[1]);
            o.y = pack_half2(acc[2], acc[3]);
            o.z = pack_half2(acc[4], acc[5]);
            o.w = pack_half2(acc[6], acc[7]);
            *(uint4*)&zl[wv * 4 + rr][8 * lane] = o;
        }
    }
    __syncthreads();

    const int cl = lane & 15;
    const int r4 = lane >> 4;
    f16x8 a[8];
#pragma unroll
    for (int ks = 0; ks < 8; ++ks)
        a[ks] = *(const f16x8*)&zl[cl][ks * 32 + 8 * r4];

    const _Float16* wcol = (const _Float16*)woT + (size_t)(wv * 16 + cl) * 256 + 8 * r4;
    f32x4 c = {0.f, 0.f, 0.f, 0.f};
#pragma unroll
    for (int ks = 0; ks < 8; ++ks) {
        f16x8 b = *(const f16x8*)(wcol + ks * 32);
        c = __builtin_amdgcn_mfma_f32_16x16x32_f16(a[ks], b, c, 0, 0, 0);
    }
#pragma unroll
    for (int j = 0; j < 4; ++j) {
        int row = base + r4 * 4 + j;
        out[(size_t)row * 64 + wv * 16 + cl] = c[j];
    }
}

// ---------------------------------------------------------------------------
extern "C" void kernel_launch(void* const* d_in, const int* in_sizes, int n_in,
                              void* d_out, int out_size, void* d_ws, size_t ws_size,
                              hipStream_t stream)
{
    const float* entity = (const float*)d_in[0];
    const float* rel    = (const float*)d_in[1];
    const float* W_h    = (const float*)d_in[2];
    const float* W_t    = (const float*)d_in[3];
    const float* W_r    = (const float*)d_in[4];
    const float* att_h  = (const float*)d_in[5];
    const float* att_t  = (const float*)d_in[6];
    const float* att_r  = (const float*)d_in[7];
    const float* W_o    = (const float*)d_in[8];
    const int*   eidx   = (const int*)d_in[9];   // [2,E]
    const int*   etype  = (const int*)d_in[10];  // [E]
    float* out = (float*)d_out;

    char* ws = (char*)d_ws;
    size_t off = 0;
    auto alloc = [&](size_t bytes) -> void* {
        void* p = ws + off;
        off += (bytes + 255) & ~(size_t)255;
        return p;
    };
    float* p_h      = (float*)alloc((size_t)N_ENT * 4 * 4);
    float* p_t      = (float*)alloc((size_t)N_ENT * 4 * 4);
    float* p_r      = (float*)alloc((size_t)N_REL * 4 * 4);
    int*   counts   = (int*)alloc((size_t)N_ENT * 4);
    int*   row_start= (int*)alloc(((size_t)N_ENT + 1) * 4);
    int*   eoff     = (int*)alloc((size_t)N_EDGE * 4);
    int*   csr_col  = (int*)alloc((size_t)N_EDGE * 4);
    float* csr_a    = (float*)alloc((size_t)N_EDGE * 4 * 4);
    __half* Zh_a    = (__half*)alloc((size_t)N_ENT * 256 * 2);
    __half* Zh_b    = (__half*)alloc((size_t)N_ENT * 256 * 2);
    unsigned short* emb_bf = (unsigned short*)alloc((size_t)N_ENT * 64 * 2);
    __half* emb_h   = (__half*)alloc((size_t)N_ENT * 64 * 2);
    unsigned short* wT     = (unsigned short*)alloc((size_t)2 * 256 * 64 * 2);
    __half* woT     = (__half*)alloc((size_t)64 * 256 * 2);

    hipMemsetAsync(counts, 0, (size_t)N_ENT * 4, stream);

    // merged prep: hist (+slot record) + bf16/fp16 conversions
    prep_kernel<<<HIST_B + EMB_B + WT_B + WOT_B, 256, 0, stream>>>(
        entity, emb_bf, emb_h, W_h, W_t, wT, W_o, woT, eidx, counts, eoff);

    // projections: h/t via MFMA (mat-split grid), relations via VALU
    const int nb = (N_ENT + 63) / 64;
    proj_mfma_kernel<<<2 * nb, 256, 0, stream>>>(
        emb_bf, wT, att_h, att_t, p_h, p_t, N_ENT, nb);
    proj_gemm_kernel<<<(N_REL + 63) / 64, 256, 0, stream>>>(
        rel, W_r, att_r, p_r, N_REL);

    scan_kernel<<<1, 1024, 0, stream>>>(counts, row_start);
    scatter_score_kernel<<<(N_EDGE + 255) / 256, 256, 0, stream>>>(
        eidx, etype, p_h, p_t, p_r, row_start, eoff, csr_col, csr_a);

    // power iteration: normalize fused with Z1 (fp16 emb gathers);
    // Z2..Z4 standalone; Z5 fused with output projection.
    norm_spmm1_kernel<<<N_ENT / 4, 256, 0, stream>>>(
        entity, emb_h, row_start, csr_col, csr_a, Zh_b);
    spmm_kernel<<<N_ENT / 4, 256, 0, stream>>>(Zh_b, entity, row_start, csr_col, csr_a, Zh_a);
    spmm_kernel<<<N_ENT / 4, 256, 0, stream>>>(Zh_a, entity, row_start, csr_col, csr_a, Zh_b);
    spmm_kernel<<<N_ENT / 4, 256, 0, stream>>>(Zh_b, entity, row_start, csr_col, csr_a, Zh_a);
    spmm_out_fused_kernel<<<N_ENT / 16, 256, 0, stream>>>(
        Zh_a, entity, row_start, csr_col, csr_a, woT, out);
}